// Round 9
// baseline (1635.057 us; speedup 1.0000x reference)
//
#include <hip/hip_runtime.h>

#define N1 1000000
#define N2 400000
#define N4 150000
#define N8 60000
#define N16 20000

constexpr float BN_EPS = 1e-5f;

__device__ __forceinline__ float lrelu(float x) { return fmaxf(x, 0.1f * x); }

// Fold all BatchNorm params into scale/shift once per call.
// fold: enc0 sc[32],sh[32] @0; encR b: sc[32],sh[32] @64+b*64; dec i: sc[64],sh[64] @320+i*128.
__global__ void k_fold(const float* g0, const float* be0, const float* m0, const float* v0,
                       const float* gR, const float* beR, const float* mR, const float* vR,
                       const float* gD, const float* beD, const float* mD, const float* vD,
                       float* fold) {
  int t = threadIdx.x;
  if (t < 32) {
    float sc = g0[t] * rsqrtf(v0[t] + BN_EPS);
    fold[t] = sc;
    fold[32 + t] = be0[t] - m0[t] * sc;
  }
  if (t < 128) {
    int b = t >> 5, c = t & 31;
    float sc = gR[b * 32 + c] * rsqrtf(vR[b * 32 + c] + BN_EPS);
    fold[64 + b * 64 + c] = sc;
    fold[64 + b * 64 + 32 + c] = beR[b * 32 + c] - mR[b * 32 + c] * sc;
  }
  for (int i = t; i < 320; i += blockDim.x) {
    int b = i >> 6, c = i & 63;
    float sc = gD[b * 64 + c] * rsqrtf(vD[b * 64 + c] + BN_EPS);
    fold[320 + b * 128 + c] = sc;
    fold[320 + b * 128 + 64 + c] = beD[b * 64 + c] - mD[b * 64 + c] * sc;
  }
}

// Build per-segment linked lists. head pre-set to -1. One 4B atomic per row.
__global__ __launch_bounds__(256) void k_fill(const int* __restrict__ idx,
                                              int* head, int* nxt, int n) {
  int i = blockIdx.x * 256 + threadIdx.x;
  if (i < n) nxt[i] = atomicExch(&head[idx[i]], i);
}

// Segment max by chained gather: one wave per segment, one thread per channel.
__global__ __launch_bounds__(256) void k_gmax(
    const float* __restrict__ src, const int* __restrict__ head,
    const int* __restrict__ nxt, float* __restrict__ dst, int nseg) {
  int t = blockIdx.x * 256 + threadIdx.x;
  int seg = t >> 6, ch = t & 63;
  if (seg >= nseg) return;
  float m = -INFINITY;
  for (int p = head[seg]; p >= 0; p = nxt[p])
    m = fmaxf(m, src[(size_t)p * 64 + ch]);
  dst[(size_t)seg * 64 + ch] = (m == -INFINITY) ? 0.0f : m;
}

// ---------------- scalar-weight GEMM kernels, 2 rows/thread, k-chunk 8 ------
// lane = output row pair (lane, lane+64) of a 128-row tile; wave w = col slice.
// Weights wave-uniform -> s_load; inputs from stride-65/33/9 LDS (conflict-free).
// k-chunk of 8: one lgkm wait per 256-FMA burst instead of per 32.

// encoder block 0: x[9] -> h[32] (lrelu,BN) -> out[64] (lrelu)
__global__ __attribute__((amdgpu_waves_per_eu(4, 4))) __launch_bounds__(256)
void k_enc0_s(
    const float* __restrict__ x,
    const float* __restrict__ W1, const float* __restrict__ b1,
    const float* __restrict__ fold,
    const float* __restrict__ W2, const float* __restrict__ b2,
    float* __restrict__ out, int n) {
  __shared__ float xS[128 * 9];
  __shared__ float hS[128 * 33];
  int t = threadIdx.x;
  int lane = t & 63;
  int w = __builtin_amdgcn_readfirstlane(t >> 6);
  int R = blockIdx.x * 128;

  {
    size_t lim = (size_t)n * 9 - 1;
    for (int i = t; i < 1152; i += 256) {
      size_t gi = (size_t)R * 9 + i;
      if (gi > lim) gi = lim;
      xS[i] = x[gi];
    }
  }
  __syncthreads();

  // phase 1: h cols 8w..8w+7 for rows lane, lane+64; K=9
  {
    const float* W1p = W1 + w * 8;
    float a0[8], a1[8];
#pragma unroll
    for (int c = 0; c < 8; ++c) { a0[c] = b1[w * 8 + c]; a1[c] = a0[c]; }
#pragma unroll
    for (int k = 0; k < 9; ++k) {
      float x0 = xS[lane * 9 + k], x1 = xS[(lane + 64) * 9 + k];
#pragma unroll
      for (int c = 0; c < 8; ++c) {
        float wv = W1p[k * 32 + c];
        a0[c] = fmaf(x0, wv, a0[c]);
        a1[c] = fmaf(x1, wv, a1[c]);
      }
    }
#pragma unroll
    for (int c = 0; c < 8; ++c) {
      float sc = fold[w * 8 + c], sh = fold[32 + w * 8 + c];
      hS[lane * 33 + w * 8 + c] = lrelu(a0[c]) * sc + sh;
      hS[(lane + 64) * 33 + w * 8 + c] = lrelu(a1[c]) * sc + sh;
    }
  }
  __syncthreads();

  // phase 2: out cols 16w..16w+15, K=32, chunks of 8
  {
    const float* W2p = W2 + w * 16;
    float o0[16], o1[16];
#pragma unroll
    for (int c = 0; c < 16; ++c) { o0[c] = b2[w * 16 + c]; o1[c] = o0[c]; }
    for (int k0 = 0; k0 < 32; k0 += 8) {
      float a0[8], a1[8];
#pragma unroll
      for (int j = 0; j < 8; ++j) {
        a0[j] = hS[lane * 33 + k0 + j];
        a1[j] = hS[(lane + 64) * 33 + k0 + j];
      }
#pragma unroll
      for (int j = 0; j < 8; ++j) {
#pragma unroll
        for (int c = 0; c < 16; ++c) {
          float wv = W2p[(k0 + j) * 64 + c];
          o0[c] = fmaf(a0[j], wv, o0[c]);
          o1[c] = fmaf(a1[j], wv, o1[c]);
        }
      }
    }
    int g0 = R + lane, g1 = R + 64 + lane;
    if (g0 < n) {
      float* op = out + (size_t)g0 * 64 + w * 16;
#pragma unroll
      for (int c = 0; c < 16; ++c) op[c] = lrelu(o0[c]);
    }
    if (g1 < n) {
      float* op = out + (size_t)g1 * 64 + w * 16;
#pragma unroll
      for (int c = 0; c < 16; ++c) op[c] = lrelu(o1[c]);
    }
  }
}

// encoder blocks 1..4: in[64] -> h[32] (lrelu,BN) -> out[64] (lrelu)
__global__ __attribute__((amdgpu_waves_per_eu(3, 3))) __launch_bounds__(256)
void k_encR_s(
    const float* __restrict__ xin,
    const float* __restrict__ W1, const float* __restrict__ b1,
    const float* __restrict__ fold,
    const float* __restrict__ W2, const float* __restrict__ b2,
    float* __restrict__ out, int n) {
  __shared__ float inS[128 * 65];
  __shared__ float hS[128 * 33];
  int t = threadIdx.x;
  int lane = t & 63;
  int w = __builtin_amdgcn_readfirstlane(t >> 6);
  int R = blockIdx.x * 128;

  for (int f = t; f < 2048; f += 256) {
    int row = f >> 4, c4 = (f & 15) << 2;
    int gr = R + row; if (gr >= n) gr = n - 1;
    float4 v = *(const float4*)(xin + (size_t)gr * 64 + c4);
    inS[row * 65 + c4 + 0] = v.x; inS[row * 65 + c4 + 1] = v.y;
    inS[row * 65 + c4 + 2] = v.z; inS[row * 65 + c4 + 3] = v.w;
  }
  __syncthreads();

  // phase 1: h cols 8w..8w+7, K=64, chunks of 8
  {
    const float* W1p = W1 + w * 8;
    float h0[8], h1[8];
#pragma unroll
    for (int c = 0; c < 8; ++c) { h0[c] = b1[w * 8 + c]; h1[c] = h0[c]; }
    for (int k0 = 0; k0 < 64; k0 += 8) {
      float a0[8], a1[8];
#pragma unroll
      for (int j = 0; j < 8; ++j) {
        a0[j] = inS[lane * 65 + k0 + j];
        a1[j] = inS[(lane + 64) * 65 + k0 + j];
      }
#pragma unroll
      for (int j = 0; j < 8; ++j) {
#pragma unroll
        for (int c = 0; c < 8; ++c) {
          float wv = W1p[(k0 + j) * 32 + c];
          h0[c] = fmaf(a0[j], wv, h0[c]);
          h1[c] = fmaf(a1[j], wv, h1[c]);
        }
      }
    }
#pragma unroll
    for (int c = 0; c < 8; ++c) {
      float sc = fold[w * 8 + c], sh = fold[32 + w * 8 + c];
      hS[lane * 33 + w * 8 + c] = lrelu(h0[c]) * sc + sh;
      hS[(lane + 64) * 33 + w * 8 + c] = lrelu(h1[c]) * sc + sh;
    }
  }
  __syncthreads();

  // phase 2: out cols 16w..16w+15, K=32, chunks of 8
  {
    const float* W2p = W2 + w * 16;
    float o0[16], o1[16];
#pragma unroll
    for (int c = 0; c < 16; ++c) { o0[c] = b2[w * 16 + c]; o1[c] = o0[c]; }
    for (int k0 = 0; k0 < 32; k0 += 8) {
      float a0[8], a1[8];
#pragma unroll
      for (int j = 0; j < 8; ++j) {
        a0[j] = hS[lane * 33 + k0 + j];
        a1[j] = hS[(lane + 64) * 33 + k0 + j];
      }
#pragma unroll
      for (int j = 0; j < 8; ++j) {
#pragma unroll
        for (int c = 0; c < 16; ++c) {
          float wv = W2p[(k0 + j) * 64 + c];
          o0[c] = fmaf(a0[j], wv, o0[c]);
          o1[c] = fmaf(a1[j], wv, o1[c]);
        }
      }
    }
    int g0 = R + lane, g1 = R + 64 + lane;
    if (g0 < n) {
      float* op = out + (size_t)g0 * 64 + w * 16;
#pragma unroll
      for (int c = 0; c < 16; ++c) op[c] = lrelu(o0[c]);
    }
    if (g1 < n) {
      float* op = out + (size_t)g1 * 64 + w * 16;
#pragma unroll
      for (int c = 0; c < 16; ++c) op[c] = lrelu(o1[c]);
    }
  }
}

// decoder block, in place on `inout`:
//   skip = lrelu(cur @ mlpW + mlpb); out = lrelu(BN([skip,last] @ decW + decb))
__global__ __attribute__((amdgpu_waves_per_eu(2, 2))) __launch_bounds__(256)
void k_dec_s(
    float* inout, const float* __restrict__ lastbuf, const int* __restrict__ idx,
    const float* __restrict__ mlpW, const float* __restrict__ mlpb,
    const float* __restrict__ decW, const float* __restrict__ decb,
    const float* __restrict__ fold, int n) {
  __shared__ float curS[128 * 65];
  __shared__ float lastS[128 * 65];
  int t = threadIdx.x;
  int lane = t & 63;
  int w = __builtin_amdgcn_readfirstlane(t >> 6);
  int R = blockIdx.x * 128;

  for (int f = t; f < 2048; f += 256) {
    int row = f >> 4, c4 = (f & 15) << 2;
    int gr = R + row; if (gr >= n) gr = n - 1;
    float4 v = *(const float4*)(inout + (size_t)gr * 64 + c4);
    curS[row * 65 + c4 + 0] = v.x; curS[row * 65 + c4 + 1] = v.y;
    curS[row * 65 + c4 + 2] = v.z; curS[row * 65 + c4 + 3] = v.w;
    int lr = idx ? idx[gr] : gr;
    float4 u = *(const float4*)(lastbuf + (size_t)lr * 64 + c4);
    lastS[row * 65 + c4 + 0] = u.x; lastS[row * 65 + c4 + 1] = u.y;
    lastS[row * 65 + c4 + 2] = u.z; lastS[row * 65 + c4 + 3] = u.w;
  }
  __syncthreads();

  // phase 1: skip cols 16w..16w+15, K=64, chunks of 8
  float s0[16], s1[16];
  {
    const float* Mp = mlpW + w * 16;
#pragma unroll
    for (int c = 0; c < 16; ++c) { s0[c] = mlpb[w * 16 + c]; s1[c] = s0[c]; }
    for (int k0 = 0; k0 < 64; k0 += 8) {
      float a0[8], a1[8];
#pragma unroll
      for (int j = 0; j < 8; ++j) {
        a0[j] = curS[lane * 65 + k0 + j];
        a1[j] = curS[(lane + 64) * 65 + k0 + j];
      }
#pragma unroll
      for (int j = 0; j < 8; ++j) {
#pragma unroll
        for (int c = 0; c < 16; ++c) {
          float wv = Mp[(k0 + j) * 64 + c];
          s0[c] = fmaf(a0[j], wv, s0[c]);
          s1[c] = fmaf(a1[j], wv, s1[c]);
        }
      }
    }
  }
  __syncthreads();  // all reads of curS done
#pragma unroll
  for (int c = 0; c < 16; ++c) {
    curS[lane * 65 + w * 16 + c] = lrelu(s0[c]);
    curS[(lane + 64) * 65 + w * 16 + c] = lrelu(s1[c]);
  }
  __syncthreads();

  // phase 2: out cols 16w..16w+15, K=128 (skip rows then last rows), chunks of 8
  {
    const float* Dp = decW + w * 16;
    float o0[16], o1[16];
#pragma unroll
    for (int c = 0; c < 16; ++c) { o0[c] = decb[w * 16 + c]; o1[c] = o0[c]; }
    for (int k0 = 0; k0 < 64; k0 += 8) {
      float a0[8], a1[8];
#pragma unroll
      for (int j = 0; j < 8; ++j) {
        a0[j] = curS[lane * 65 + k0 + j];
        a1[j] = curS[(lane + 64) * 65 + k0 + j];
      }
#pragma unroll
      for (int j = 0; j < 8; ++j) {
#pragma unroll
        for (int c = 0; c < 16; ++c) {
          float wv = Dp[(k0 + j) * 64 + c];
          o0[c] = fmaf(a0[j], wv, o0[c]);
          o1[c] = fmaf(a1[j], wv, o1[c]);
        }
      }
    }
    for (int k0 = 0; k0 < 64; k0 += 8) {
      float a0[8], a1[8];
#pragma unroll
      for (int j = 0; j < 8; ++j) {
        a0[j] = lastS[lane * 65 + k0 + j];
        a1[j] = lastS[(lane + 64) * 65 + k0 + j];
      }
#pragma unroll
      for (int j = 0; j < 8; ++j) {
#pragma unroll
        for (int c = 0; c < 16; ++c) {
          float wv = Dp[(64 + k0 + j) * 64 + c];
          o0[c] = fmaf(a0[j], wv, o0[c]);
          o1[c] = fmaf(a1[j], wv, o1[c]);
        }
      }
    }
    int g0 = R + lane, g1 = R + 64 + lane;
    if (g0 < n) {
      float* op = inout + (size_t)g0 * 64 + w * 16;
#pragma unroll
      for (int c = 0; c < 16; ++c) {
        float sc = fold[w * 16 + c], sh = fold[64 + w * 16 + c];
        op[c] = lrelu(o0[c] * sc + sh);
      }
    }
    if (g1 < n) {
      float* op = inout + (size_t)g1 * 64 + w * 16;
#pragma unroll
      for (int c = 0; c < 16; ++c) {
        float sc = fold[w * 16 + c], sh = fold[64 + w * 16 + c];
        op[c] = lrelu(o1[c] * sc + sh);
      }
    }
  }
}

extern "C" void kernel_launch(void* const* d_in, const int* in_sizes, int n_in,
                              void* d_out, int out_size, void* d_ws, size_t ws_size,
                              hipStream_t stream) {
  const float* pt   = (const float*)d_in[0];
  const int* inv2   = (const int*)d_in[1];
  const int* inv4   = (const int*)d_in[2];
  const int* inv8   = (const int*)d_in[3];
  const int* inv16  = (const int*)d_in[4];
  const float* e0W1 = (const float*)d_in[5];
  const float* e0b1 = (const float*)d_in[6];
  const float* e0g  = (const float*)d_in[7];
  const float* e0be = (const float*)d_in[8];
  const float* e0m  = (const float*)d_in[9];
  const float* e0v  = (const float*)d_in[10];
  const float* e0W2 = (const float*)d_in[11];
  const float* e0b2 = (const float*)d_in[12];
  const float* eRW1 = (const float*)d_in[13];
  const float* eRb1 = (const float*)d_in[14];
  const float* eRg  = (const float*)d_in[15];
  const float* eRbe = (const float*)d_in[16];
  const float* eRm  = (const float*)d_in[17];
  const float* eRv  = (const float*)d_in[18];
  const float* eRW2 = (const float*)d_in[19];
  const float* eRb2 = (const float*)d_in[20];
  const float* mlpW = (const float*)d_in[21];
  const float* mlpb = (const float*)d_in[22];
  const float* decW = (const float*)d_in[23];
  const float* decb = (const float*)d_in[24];
  const float* decg = (const float*)d_in[25];
  const float* decbe= (const float*)d_in[26];
  const float* decm = (const float*)d_in[27];
  const float* decv = (const float*)d_in[28];

  float* s1 = (float*)d_out;
  float* s2 = s1 + (size_t)N1 * 64;
  float* s3 = s2 + (size_t)N2 * 64;
  float* s4 = s3 + (size_t)N4 * 64;
  float* s5 = s4 + (size_t)N8 * 64;

  // workspace: fold | oA (N2*64 f) | oB (N4*64 f) | head (N2 i) | nxt (N1 i)
  float* fold = (float*)d_ws;
  float* oA   = fold + 1024;
  float* oB   = oA + (size_t)N2 * 64;
  int* head   = (int*)(oB + (size_t)N4 * 64);
  int* nxt    = head + N2;

  k_fold<<<1, 320, 0, stream>>>(e0g, e0be, e0m, e0v, eRg, eRbe, eRm, eRv,
                                decg, decbe, decm, decv, fold);

  // ---- level 1: enc0 on N1, pool -> oA [N2] ----
  hipMemsetAsync(head, 0xFF, (size_t)N2 * 4, stream);
  k_fill<<<(N1 + 255) / 256, 256, 0, stream>>>(inv2, head, nxt, N1);
  k_enc0_s<<<(N1 + 127) / 128, 256, 0, stream>>>(pt, e0W1, e0b1, fold, e0W2, e0b2, s1, N1);
  k_gmax<<<((size_t)N2 * 64 + 255) / 256, 256, 0, stream>>>(s1, head, nxt, oA, N2);

  // ---- level 2: encR[0] on N2, pool -> oB [N4] ----
  hipMemsetAsync(head, 0xFF, (size_t)N4 * 4, stream);
  k_fill<<<(N2 + 255) / 256, 256, 0, stream>>>(inv4, head, nxt, N2);
  k_encR_s<<<(N2 + 127) / 128, 256, 0, stream>>>(oA, eRW1 + 0 * 2048, eRb1 + 0 * 32,
                                                 fold + 64 + 0 * 64, eRW2 + 0 * 2048,
                                                 eRb2 + 0 * 64, s2, N2);
  k_gmax<<<((size_t)N4 * 64 + 255) / 256, 256, 0, stream>>>(s2, head, nxt, oB, N4);

  // ---- level 3: encR[1] on N4, pool -> oA [N8] ----
  hipMemsetAsync(head, 0xFF, (size_t)N8 * 4, stream);
  k_fill<<<(N4 + 255) / 256, 256, 0, stream>>>(inv8, head, nxt, N4);
  k_encR_s<<<(N4 + 127) / 128, 256, 0, stream>>>(oB, eRW1 + 1 * 2048, eRb1 + 1 * 32,
                                                 fold + 64 + 1 * 64, eRW2 + 1 * 2048,
                                                 eRb2 + 1 * 64, s3, N4);
  k_gmax<<<((size_t)N8 * 64 + 255) / 256, 256, 0, stream>>>(s3, head, nxt, oA, N8);

  // ---- level 4: encR[2] on N8, pool -> oB [N16] ----
  hipMemsetAsync(head, 0xFF, (size_t)N16 * 4, stream);
  k_fill<<<(N8 + 255) / 256, 256, 0, stream>>>(inv16, head, nxt, N8);
  k_encR_s<<<(N8 + 127) / 128, 256, 0, stream>>>(oA, eRW1 + 2 * 2048, eRb1 + 2 * 32,
                                                 fold + 64 + 2 * 64, eRW2 + 2 * 2048,
                                                 eRb2 + 2 * 64, s4, N8);
  k_gmax<<<((size_t)N16 * 64 + 255) / 256, 256, 0, stream>>>(s4, head, nxt, oB, N16);

  // ---- level 5: encR[3] on N16 ----
  k_encR_s<<<(N16 + 127) / 128, 256, 0, stream>>>(oB, eRW1 + 3 * 2048, eRb1 + 3 * 32,
                                                  fold + 64 + 3 * 64, eRW2 + 3 * 2048,
                                                  eRb2 + 3 * 64, s5, N16);

  // ---- decoders (in place, top-down) ----
  k_dec_s<<<(N16 + 127) / 128, 256, 0, stream>>>(s5, s5, nullptr, mlpW + 0 * 4096, mlpb + 0 * 64,
                                                 decW + 0 * 8192, decb + 0 * 64,
                                                 fold + 320 + 0 * 128, N16);
  k_dec_s<<<(N8 + 127) / 128, 256, 0, stream>>>(s4, s5, inv16, mlpW + 1 * 4096, mlpb + 1 * 64,
                                                decW + 1 * 8192, decb + 1 * 64,
                                                fold + 320 + 1 * 128, N8);
  k_dec_s<<<(N4 + 127) / 128, 256, 0, stream>>>(s3, s4, inv8, mlpW + 2 * 4096, mlpb + 2 * 64,
                                                decW + 2 * 8192, decb + 2 * 64,
                                                fold + 320 + 2 * 128, N4);
  k_dec_s<<<(N2 + 127) / 128, 256, 0, stream>>>(s2, s3, inv4, mlpW + 3 * 4096, mlpb + 3 * 64,
                                                decW + 3 * 8192, decb + 3 * 64,
                                                fold + 320 + 3 * 128, N2);
  k_dec_s<<<(N1 + 127) / 128, 256, 0, stream>>>(s1, s2, inv2, mlpW + 4 * 4096, mlpb + 4 * 64,
                                                decW + 4 * 8192, decb + 4 * 64,
                                                fold + 320 + 4 * 128, N1);
}

// Round 10
// 1095.692 us; speedup vs baseline: 1.4923x; 1.4923x over previous
//
#include <hip/hip_runtime.h>

#define N1 1000000
#define N2 400000
#define N4 150000
#define N8 60000
#define N16 20000

constexpr float BN_EPS = 1e-5f;

__device__ __forceinline__ float lrelu(float x) { return fmaxf(x, 0.1f * x); }

// Fold all BatchNorm params into scale/shift once per call.
// fold: enc0 sc[32],sh[32] @0; encR b: sc[32],sh[32] @64+b*64; dec i: sc[64],sh[64] @320+i*128.
__global__ void k_fold(const float* g0, const float* be0, const float* m0, const float* v0,
                       const float* gR, const float* beR, const float* mR, const float* vR,
                       const float* gD, const float* beD, const float* mD, const float* vD,
                       float* fold) {
  int t = threadIdx.x;
  if (t < 32) {
    float sc = g0[t] * rsqrtf(v0[t] + BN_EPS);
    fold[t] = sc;
    fold[32 + t] = be0[t] - m0[t] * sc;
  }
  if (t < 128) {
    int b = t >> 5, c = t & 31;
    float sc = gR[b * 32 + c] * rsqrtf(vR[b * 32 + c] + BN_EPS);
    fold[64 + b * 64 + c] = sc;
    fold[64 + b * 64 + 32 + c] = beR[b * 32 + c] - mR[b * 32 + c] * sc;
  }
  for (int i = t; i < 320; i += blockDim.x) {
    int b = i >> 6, c = i & 63;
    float sc = gD[b * 64 + c] * rsqrtf(vD[b * 64 + c] + BN_EPS);
    fold[320 + b * 128 + c] = sc;
    fold[320 + b * 128 + 64 + c] = beD[b * 64 + c] - mD[b * 64 + c] * sc;
  }
}

// Build per-segment linked lists. head pre-set to -1. One 4B atomic per row.
__global__ __launch_bounds__(256) void k_fill(const int* __restrict__ idx,
                                              int* head, int* nxt, int n) {
  int i = blockIdx.x * 256 + threadIdx.x;
  if (i < n) nxt[i] = atomicExch(&head[idx[i]], i);
}

// Segment max by chained gather: one wave per segment, one thread per channel.
__global__ __launch_bounds__(256) void k_gmax(
    const float* __restrict__ src, const int* __restrict__ head,
    const int* __restrict__ nxt, float* __restrict__ dst, int nseg) {
  int t = blockIdx.x * 256 + threadIdx.x;
  int seg = t >> 6, ch = t & 63;
  if (seg >= nseg) return;
  float m = -INFINITY;
  for (int p = head[seg]; p >= 0; p = nxt[p])
    m = fmaxf(m, src[(size_t)p * 64 + ch]);
  dst[(size_t)seg * 64 + ch] = (m == -INFINITY) ? 0.0f : m;
}

// ---------------- scalar-weight GEMM kernels (R8 structure) ----------------
// lane = output row (64 rows/block), wave w = 16-col (or 8-col) slice.
// Weights wave-uniform -> s_load; inputs from stride-65/33/9 LDS (2-way max,
// free). Per-thread state ~50 VGPRs -> no spill, high occupancy.

// encoder block 0: x[9] -> h[32] (lrelu,BN) -> out[64] (lrelu)
__global__ __launch_bounds__(256) void k_enc0_s(
    const float* __restrict__ x,
    const float* __restrict__ W1, const float* __restrict__ b1,
    const float* __restrict__ fold,
    const float* __restrict__ W2, const float* __restrict__ b2,
    float* __restrict__ out, int n) {
  __shared__ float xS[64 * 9];
  __shared__ float hS[64 * 33];
  int t = threadIdx.x;
  int lane = t & 63;
  int w = __builtin_amdgcn_readfirstlane(t >> 6);
  int R = blockIdx.x * 64;

  {
    size_t lim = (size_t)n * 9 - 1;
    for (int i = t; i < 576; i += 256) {
      size_t gi = (size_t)R * 9 + i;
      if (gi > lim) gi = lim;
      xS[i] = x[gi];
    }
  }
  __syncthreads();

  // phase 1: h cols 8w..8w+7, K=9
  {
    const float* W1p = W1 + w * 8;
    float acc[8];
#pragma unroll
    for (int c = 0; c < 8; ++c) acc[c] = b1[w * 8 + c];
    for (int k = 0; k < 9; ++k) {
      float a = xS[lane * 9 + k];
#pragma unroll
      for (int c = 0; c < 8; ++c) acc[c] = fmaf(a, W1p[k * 32 + c], acc[c]);
    }
#pragma unroll
    for (int c = 0; c < 8; ++c) {
      float sc = fold[w * 8 + c], sh = fold[32 + w * 8 + c];
      hS[lane * 33 + w * 8 + c] = lrelu(acc[c]) * sc + sh;
    }
  }
  __syncthreads();

  // phase 2: out cols 16w..16w+15, K=32
  {
    const float* W2p = W2 + w * 16;
    float o[16];
#pragma unroll
    for (int c = 0; c < 16; ++c) o[c] = b2[w * 16 + c];
    for (int k = 0; k < 32; ++k) {
      float a = hS[lane * 33 + k];
#pragma unroll
      for (int c = 0; c < 16; ++c) o[c] = fmaf(a, W2p[k * 64 + c], o[c]);
    }
    int gr = R + lane;
    if (gr < n) {
      float* op = out + (size_t)gr * 64 + w * 16;
#pragma unroll
      for (int c = 0; c < 16; ++c) op[c] = lrelu(o[c]);
    }
  }
}

// encoder blocks 1..4: in[64] -> h[32] (lrelu,BN) -> out[64] (lrelu)
__global__ __launch_bounds__(256) void k_encR_s(
    const float* __restrict__ xin,
    const float* __restrict__ W1, const float* __restrict__ b1,
    const float* __restrict__ fold,
    const float* __restrict__ W2, const float* __restrict__ b2,
    float* __restrict__ out, int n) {
  __shared__ float inS[64 * 65];
  __shared__ float hS[64 * 33];
  int t = threadIdx.x;
  int lane = t & 63;
  int w = __builtin_amdgcn_readfirstlane(t >> 6);
  int R = blockIdx.x * 64;

  for (int f = t; f < 1024; f += 256) {
    int row = f >> 4, c4 = (f & 15) << 2;
    int gr = R + row; if (gr >= n) gr = n - 1;
    float4 v = *(const float4*)(xin + (size_t)gr * 64 + c4);
    inS[row * 65 + c4 + 0] = v.x; inS[row * 65 + c4 + 1] = v.y;
    inS[row * 65 + c4 + 2] = v.z; inS[row * 65 + c4 + 3] = v.w;
  }
  __syncthreads();

  // phase 1: h cols 8w..8w+7, K=64
  {
    const float* W1p = W1 + w * 8;
    float acc[8];
#pragma unroll
    for (int c = 0; c < 8; ++c) acc[c] = b1[w * 8 + c];
    for (int k = 0; k < 64; ++k) {
      float a = inS[lane * 65 + k];
#pragma unroll
      for (int c = 0; c < 8; ++c) acc[c] = fmaf(a, W1p[k * 32 + c], acc[c]);
    }
#pragma unroll
    for (int c = 0; c < 8; ++c) {
      float sc = fold[w * 8 + c], sh = fold[32 + w * 8 + c];
      hS[lane * 33 + w * 8 + c] = lrelu(acc[c]) * sc + sh;
    }
  }
  __syncthreads();

  // phase 2: out cols 16w..16w+15, K=32
  {
    const float* W2p = W2 + w * 16;
    float o[16];
#pragma unroll
    for (int c = 0; c < 16; ++c) o[c] = b2[w * 16 + c];
    for (int k = 0; k < 32; ++k) {
      float a = hS[lane * 33 + k];
#pragma unroll
      for (int c = 0; c < 16; ++c) o[c] = fmaf(a, W2p[k * 64 + c], o[c]);
    }
    int gr = R + lane;
    if (gr < n) {
      float* op = out + (size_t)gr * 64 + w * 16;
#pragma unroll
      for (int c = 0; c < 16; ++c) op[c] = lrelu(o[c]);
    }
  }
}

// lastT = src @ decW[64:128] + decb  (no activation), rows = n (prev level)
__global__ __launch_bounds__(256) void k_lastT(
    const float* __restrict__ src, const float* __restrict__ decW,
    const float* __restrict__ decb, float* __restrict__ lT, int n) {
  __shared__ float sS[64 * 65];
  int t = threadIdx.x;
  int lane = t & 63;
  int w = __builtin_amdgcn_readfirstlane(t >> 6);
  int R = blockIdx.x * 64;

  for (int f = t; f < 1024; f += 256) {
    int row = f >> 4, c4 = (f & 15) << 2;
    int gr = R + row; if (gr >= n) gr = n - 1;
    float4 v = *(const float4*)(src + (size_t)gr * 64 + c4);
    sS[row * 65 + c4 + 0] = v.x; sS[row * 65 + c4 + 1] = v.y;
    sS[row * 65 + c4 + 2] = v.z; sS[row * 65 + c4 + 3] = v.w;
  }
  __syncthreads();

  const float* Dp = decW + 64 * 64 + w * 16;  // bottom half rows
  float o[16];
#pragma unroll
  for (int c = 0; c < 16; ++c) o[c] = decb[w * 16 + c];
  for (int k = 0; k < 64; ++k) {
    float a = sS[lane * 65 + k];
#pragma unroll
    for (int c = 0; c < 16; ++c) o[c] = fmaf(a, Dp[k * 64 + c], o[c]);
  }
  int gr = R + lane;
  if (gr < n) {
    float* op = lT + (size_t)gr * 64 + w * 16;
#pragma unroll
    for (int c = 0; c < 16; ++c) op[c] = o[c];
  }
}

// decoder: out = lrelu(BN(lrelu(cur@mlpW+mlpb) @ decW[0:64] + lastT[lrow]))
// In place on `inout`. Only curS in LDS (16.6 KB) -> high occupancy.
__global__ __launch_bounds__(256) void k_dec2(
    float* inout, const float* __restrict__ lT, const int* __restrict__ idx,
    const float* __restrict__ mlpW, const float* __restrict__ mlpb,
    const float* __restrict__ decW, const float* __restrict__ fold, int n) {
  __shared__ float curS[64 * 65];
  int t = threadIdx.x;
  int lane = t & 63;
  int w = __builtin_amdgcn_readfirstlane(t >> 6);
  int R = blockIdx.x * 64;

  for (int f = t; f < 1024; f += 256) {
    int row = f >> 4, c4 = (f & 15) << 2;
    int gr = R + row; if (gr >= n) gr = n - 1;
    float4 v = *(const float4*)(inout + (size_t)gr * 64 + c4);
    curS[row * 65 + c4 + 0] = v.x; curS[row * 65 + c4 + 1] = v.y;
    curS[row * 65 + c4 + 2] = v.z; curS[row * 65 + c4 + 3] = v.w;
  }
  __syncthreads();

  // phase 1: skip cols 16w..16w+15, K=64
  float sk[16];
  {
    const float* Mp = mlpW + w * 16;
#pragma unroll
    for (int c = 0; c < 16; ++c) sk[c] = mlpb[w * 16 + c];
    for (int k = 0; k < 64; ++k) {
      float a = curS[lane * 65 + k];
#pragma unroll
      for (int c = 0; c < 16; ++c) sk[c] = fmaf(a, Mp[k * 64 + c], sk[c]);
    }
  }
  __syncthreads();  // all reads of curS done
#pragma unroll
  for (int c = 0; c < 16; ++c)
    curS[lane * 65 + w * 16 + c] = lrelu(sk[c]);
  __syncthreads();

  // phase 2: out cols 16w..16w+15 = skip @ decW_top + lastT[lrow], K=64
  {
    int grc = R + lane; if (grc >= n) grc = n - 1;
    int g = idx ? idx[grc] : grc;
    const float* lp = lT + (size_t)g * 64 + w * 16;
    float4 l0 = *(const float4*)(lp + 0);
    float4 l1 = *(const float4*)(lp + 4);
    float4 l2 = *(const float4*)(lp + 8);
    float4 l3 = *(const float4*)(lp + 12);
    float o[16];
    o[0] = l0.x; o[1] = l0.y; o[2] = l0.z; o[3] = l0.w;
    o[4] = l1.x; o[5] = l1.y; o[6] = l1.z; o[7] = l1.w;
    o[8] = l2.x; o[9] = l2.y; o[10] = l2.z; o[11] = l2.w;
    o[12] = l3.x; o[13] = l3.y; o[14] = l3.z; o[15] = l3.w;

    const float* Dp = decW + w * 16;  // top half rows
    for (int k = 0; k < 64; ++k) {
      float a = curS[lane * 65 + k];
#pragma unroll
      for (int c = 0; c < 16; ++c) o[c] = fmaf(a, Dp[k * 64 + c], o[c]);
    }
    int gr = R + lane;
    if (gr < n) {
      float* op = inout + (size_t)gr * 64 + w * 16;
#pragma unroll
      for (int c = 0; c < 16; ++c) {
        float sc = fold[w * 16 + c], sh = fold[64 + w * 16 + c];
        op[c] = lrelu(o[c] * sc + sh);
      }
    }
  }
}

extern "C" void kernel_launch(void* const* d_in, const int* in_sizes, int n_in,
                              void* d_out, int out_size, void* d_ws, size_t ws_size,
                              hipStream_t stream) {
  const float* pt   = (const float*)d_in[0];
  const int* inv2   = (const int*)d_in[1];
  const int* inv4   = (const int*)d_in[2];
  const int* inv8   = (const int*)d_in[3];
  const int* inv16  = (const int*)d_in[4];
  const float* e0W1 = (const float*)d_in[5];
  const float* e0b1 = (const float*)d_in[6];
  const float* e0g  = (const float*)d_in[7];
  const float* e0be = (const float*)d_in[8];
  const float* e0m  = (const float*)d_in[9];
  const float* e0v  = (const float*)d_in[10];
  const float* e0W2 = (const float*)d_in[11];
  const float* e0b2 = (const float*)d_in[12];
  const float* eRW1 = (const float*)d_in[13];
  const float* eRb1 = (const float*)d_in[14];
  const float* eRg  = (const float*)d_in[15];
  const float* eRbe = (const float*)d_in[16];
  const float* eRm  = (const float*)d_in[17];
  const float* eRv  = (const float*)d_in[18];
  const float* eRW2 = (const float*)d_in[19];
  const float* eRb2 = (const float*)d_in[20];
  const float* mlpW = (const float*)d_in[21];
  const float* mlpb = (const float*)d_in[22];
  const float* decW = (const float*)d_in[23];
  const float* decb = (const float*)d_in[24];
  const float* decg = (const float*)d_in[25];
  const float* decbe= (const float*)d_in[26];
  const float* decm = (const float*)d_in[27];
  const float* decv = (const float*)d_in[28];

  float* s1 = (float*)d_out;
  float* s2 = s1 + (size_t)N1 * 64;
  float* s3 = s2 + (size_t)N2 * 64;
  float* s4 = s3 + (size_t)N4 * 64;
  float* s5 = s4 + (size_t)N8 * 64;

  // workspace: fold | oA (N2*64 f, reused as lastT in dec phase) | oB (N4*64 f)
  //            | head (N2 i) | nxt (N1 i)
  float* fold = (float*)d_ws;
  float* oA   = fold + 1024;
  float* oB   = oA + (size_t)N2 * 64;
  int* head   = (int*)(oB + (size_t)N4 * 64);
  int* nxt    = head + N2;
  float* lT   = oA;  // free after encoders

  k_fold<<<1, 320, 0, stream>>>(e0g, e0be, e0m, e0v, eRg, eRbe, eRm, eRv,
                                decg, decbe, decm, decv, fold);

  // ---- level 1: enc0 on N1, pool -> oA [N2] ----
  hipMemsetAsync(head, 0xFF, (size_t)N2 * 4, stream);
  k_fill<<<(N1 + 255) / 256, 256, 0, stream>>>(inv2, head, nxt, N1);
  k_enc0_s<<<(N1 + 63) / 64, 256, 0, stream>>>(pt, e0W1, e0b1, fold, e0W2, e0b2, s1, N1);
  k_gmax<<<((size_t)N2 * 64 + 255) / 256, 256, 0, stream>>>(s1, head, nxt, oA, N2);

  // ---- level 2: encR[0] on N2, pool -> oB [N4] ----
  hipMemsetAsync(head, 0xFF, (size_t)N4 * 4, stream);
  k_fill<<<(N2 + 255) / 256, 256, 0, stream>>>(inv4, head, nxt, N2);
  k_encR_s<<<(N2 + 63) / 64, 256, 0, stream>>>(oA, eRW1 + 0 * 2048, eRb1 + 0 * 32,
                                               fold + 64 + 0 * 64, eRW2 + 0 * 2048,
                                               eRb2 + 0 * 64, s2, N2);
  k_gmax<<<((size_t)N4 * 64 + 255) / 256, 256, 0, stream>>>(s2, head, nxt, oB, N4);

  // ---- level 3: encR[1] on N4, pool -> oA [N8] ----
  hipMemsetAsync(head, 0xFF, (size_t)N8 * 4, stream);
  k_fill<<<(N4 + 255) / 256, 256, 0, stream>>>(inv8, head, nxt, N4);
  k_encR_s<<<(N4 + 63) / 64, 256, 0, stream>>>(oB, eRW1 + 1 * 2048, eRb1 + 1 * 32,
                                               fold + 64 + 1 * 64, eRW2 + 1 * 2048,
                                               eRb2 + 1 * 64, s3, N4);
  k_gmax<<<((size_t)N8 * 64 + 255) / 256, 256, 0, stream>>>(s3, head, nxt, oA, N8);

  // ---- level 4: encR[2] on N8, pool -> oB [N16] ----
  hipMemsetAsync(head, 0xFF, (size_t)N16 * 4, stream);
  k_fill<<<(N8 + 255) / 256, 256, 0, stream>>>(inv16, head, nxt, N8);
  k_encR_s<<<(N8 + 63) / 64, 256, 0, stream>>>(oA, eRW1 + 2 * 2048, eRb1 + 2 * 32,
                                               fold + 64 + 2 * 64, eRW2 + 2 * 2048,
                                               eRb2 + 2 * 64, s4, N8);
  k_gmax<<<((size_t)N16 * 64 + 255) / 256, 256, 0, stream>>>(s4, head, nxt, oB, N16);

  // ---- level 5: encR[3] on N16 ----
  k_encR_s<<<(N16 + 63) / 64, 256, 0, stream>>>(oB, eRW1 + 3 * 2048, eRb1 + 3 * 32,
                                                fold + 64 + 3 * 64, eRW2 + 3 * 2048,
                                                eRb2 + 3 * 64, s5, N16);

  // ---- decoders: lastT = prev_out @ decW_bot + decb, then fused dec ----
  // L0: last = p5 itself
  k_lastT<<<(N16 + 63) / 64, 256, 0, stream>>>(s5, decW + 0 * 8192, decb + 0 * 64, lT, N16);
  k_dec2<<<(N16 + 63) / 64, 256, 0, stream>>>(s5, lT, nullptr, mlpW + 0 * 4096, mlpb + 0 * 64,
                                              decW + 0 * 8192, fold + 320 + 0 * 128, N16);
  // L1: last = p5f (s5)
  k_lastT<<<(N16 + 63) / 64, 256, 0, stream>>>(s5, decW + 1 * 8192, decb + 1 * 64, lT, N16);
  k_dec2<<<(N8 + 63) / 64, 256, 0, stream>>>(s4, lT, inv16, mlpW + 1 * 4096, mlpb + 1 * 64,
                                             decW + 1 * 8192, fold + 320 + 1 * 128, N8);
  // L2: last = p4f (s4)
  k_lastT<<<(N8 + 63) / 64, 256, 0, stream>>>(s4, decW + 2 * 8192, decb + 2 * 64, lT, N8);
  k_dec2<<<(N4 + 63) / 64, 256, 0, stream>>>(s3, lT, inv8, mlpW + 2 * 4096, mlpb + 2 * 64,
                                             decW + 2 * 8192, fold + 320 + 2 * 128, N4);
  // L3: last = p3f (s3)
  k_lastT<<<(N4 + 63) / 64, 256, 0, stream>>>(s3, decW + 3 * 8192, decb + 3 * 64, lT, N4);
  k_dec2<<<(N2 + 63) / 64, 256, 0, stream>>>(s2, lT, inv4, mlpW + 3 * 4096, mlpb + 3 * 64,
                                             decW + 3 * 8192, fold + 320 + 3 * 128, N2);
  // L4: last = p2f (s2)
  k_lastT<<<(N2 + 63) / 64, 256, 0, stream>>>(s2, decW + 4 * 8192, decb + 4 * 64, lT, N2);
  k_dec2<<<(N1 + 63) / 64, 256, 0, stream>>>(s1, lT, inv2, mlpW + 4 * 4096, mlpb + 4 * 64,
                                             decW + 4 * 8192, fold + 320 + 4 * 128, N1);
}